// Round 12
// baseline (95.373 us; speedup 1.0000x reference)
//
#include <hip/hip_runtime.h>
#include <math.h>

// Problem constants
#define BB 512
#define VV 2
#define MM 1024
#define DD 128
#define KMAX 50
#define TOPK 15
#define INV_T (1.0f/0.07f)

// ---------------- Workspace layout (byte offsets) ----------------
#define OFF_ANCH  0                      // bf16 [MM][DD]   256 KB
#define OFF_A2    262144                 // f32  [MM]         4 KB
#define OFF_ACCT  266240                 // f32  [BB][MM]     2 MB : accT[b][i] = acc(i,b)
#define OFF_PARTR 2363392                // f32  [16][MM]    64 KB : row partial expsums
#define OFF_PARTC 2428928                // f32  [64][MM]   256 KB : col partial expsums
#define OFF_LSPOS 2691072                // f32  [512]        2 KB : positive-pair logit

typedef __attribute__((ext_vector_type(8))) short bf16x8;
typedef __attribute__((ext_vector_type(4))) float f32x4;

// f32 -> bf16 (RNE)
__device__ __forceinline__ short f2bf(float x)
{
    union { float f; unsigned u; } a; a.f = x;
    return (short)((a.u + 0x7FFFu + ((a.u >> 16) & 1u)) >> 16);
}

// convert 8 f32 (two float4) to bf16x8, accumulating sum of squares
__device__ __forceinline__ bf16x8 cvt8(float4 p0, float4 p1, float& nacc)
{
    float v[8] = {p0.x, p0.y, p0.z, p0.w, p1.x, p1.y, p1.z, p1.w};
    bf16x8 r;
    #pragma unroll
    for (int e = 0; e < 8; ++e) {
        nacc = fmaf(v[e], v[e], nacc);
        r[e] = f2bf(v[e]);
    }
    return r;
}

// ---------------------------------------------------------------------------
// K0: anchor (transposed features) -> bf16 + exact f32 norms.  (R6 verbatim)
// Additionally zero-fills partR+partC (320 KB; ws is poisoned to 0xAA).
// 256 blocks x 256 thr; wave per row.
// ---------------------------------------------------------------------------
__global__ __launch_bounds__(256) void k0_anchor(
    const float* __restrict__ feat,
    unsigned* __restrict__ anchor_u,     // bf16 pairs packed as u32
    float* __restrict__ a2,
    float4* __restrict__ partzero)       // partR..partC region as float4
{
    const int row  = blockIdx.x * 4 + (threadIdx.x >> 6);
    const int lane = threadIdx.x & 63;
    const int frow = (row & (BB - 1)) * VV + (row >> 9);
    float2 v = *(const float2*)&feat[(size_t)frow * DD + lane * 2];
    unsigned lo = (unsigned)(unsigned short)f2bf(v.x);
    unsigned hi = (unsigned)(unsigned short)f2bf(v.y);
    anchor_u[row * (DD / 2) + lane] = lo | (hi << 16);
    float sq = v.x * v.x + v.y * v.y;
    #pragma unroll
    for (int off = 32; off > 0; off >>= 1) sq += __shfl_xor(sq, off);
    if (lane == 0) a2[row] = sq;

    const int gid = blockIdx.x * 256 + threadIdx.x;   // 0..65535
    if (gid < (320 * 1024 / 16))                      // 320 KB of zeros
        partzero[gid] = make_float4(0.f, 0.f, 0.f, 0.f);
}

// ---------------------------------------------------------------------------
// K1: neighbor MFMA GEMM -> accT[b][i].  (R6 verbatim: grid (128,4), 2x2
// waves, block 64 neighbor rows x 256 anchor cols via jt loop.)
// A side gathered from saved (f32->bf16 in-register + exact shfl norms);
// B side reads K0's staged bf16 anchor.
// C layout (mfma_f32_16x16x32_bf16): col = lane&15, row(k) = (lane>>4)*4 + reg.
// ---------------------------------------------------------------------------
__global__ __launch_bounds__(256) void k1_acc(
    const short* __restrict__ anchor,    // bf16 [MM][DD]
    const float* __restrict__ a2,
    const int* __restrict__ indices,
    const float* __restrict__ saved, const int* __restrict__ rks,
    float* __restrict__ accT)
{
    const int tid = threadIdx.x;
    const int lane = tid & 63;
    const int wid = tid >> 6;
    const int lr = lane & 15;
    const int lg = lane >> 4;
    const int wr = wid >> 1;
    const int wc = wid & 1;
    const int m0 = blockIdx.x * 64 + wr * 32;        // neighbor row base

    // A side: gather 2 b-groups' saved rows (k = lr; k=15 masked in epilogue)
    int aidx[2];
    #pragma unroll
    for (int tm = 0; tm < 2; ++tm) {
        int b = (m0 >> 4) + tm;
        aidx[tm] = rks[(size_t)indices[b] * KMAX + lr];
    }
    bf16x8 af[2][4];
    float nnA[2] = {0.f, 0.f};
    #pragma unroll
    for (int tm = 0; tm < 2; ++tm)
        #pragma unroll
        for (int kc = 0; kc < 4; ++kc) {
            const float4* p = (const float4*)&saved[(size_t)aidx[tm] * DD + kc * 32 + lg * 8];
            af[tm][kc] = cvt8(p[0], p[1], nnA[tm]);
        }
    #pragma unroll
    for (int tm = 0; tm < 2; ++tm) {
        nnA[tm] += __shfl_xor(nnA[tm], 16);
        nnA[tm] += __shfl_xor(nnA[tm], 32);          // lane: full norm of row lr
    }
    float nnAr[2][4];
    #pragma unroll
    for (int tm = 0; tm < 2; ++tm)
        #pragma unroll
        for (int r = 0; r < 4; ++r)
            nnAr[tm][r] = __shfl(nnA[tm], lg * 4 + r);   // norm of C-row lg*4+r

    #pragma unroll
    for (int jt = 0; jt < 2; ++jt) {
        const int j0 = blockIdx.y * 256 + jt * 128 + wc * 64;
        f32x4 acc[2][4];
        #pragma unroll
        for (int a = 0; a < 2; ++a)
            #pragma unroll
            for (int b = 0; b < 4; ++b) acc[a][b] = (f32x4){0.f, 0.f, 0.f, 0.f};
        #pragma unroll
        for (int kc = 0; kc < 4; ++kc) {
            bf16x8 bf[4];
            #pragma unroll
            for (int tn = 0; tn < 4; ++tn)
                bf[tn] = *(const bf16x8*)&anchor[(size_t)(j0 + tn * 16 + lr) * DD + kc * 32 + lg * 8];
            #pragma unroll
            for (int tm = 0; tm < 2; ++tm)
                #pragma unroll
                for (int tn = 0; tn < 4; ++tn)
                    acc[tm][tn] = __builtin_amdgcn_mfma_f32_16x16x32_bf16(
                        af[tm][kc], bf[tn], acc[tm][tn], 0, 0, 0);
        }
        #pragma unroll
        for (int tm = 0; tm < 2; ++tm) {
            const int b = (m0 >> 4) + tm;
            #pragma unroll
            for (int tn = 0; tn < 4; ++tn) {
                const float a2j = a2[j0 + tn * 16 + lr];
                float s = 0.f;
                #pragma unroll
                for (int r = 0; r < 4; ++r) {
                    float g = acc[tm][tn][r];
                    float sq = fmaxf(fmaf(-2.f, g, a2j + nnAr[tm][r]), 0.f);
                    float d = __builtin_amdgcn_sqrtf(sq);
                    float f = fmaf(__builtin_amdgcn_rcpf(1.f + d), INV_T, INV_T);
                    if (lg == 3 && r == 3) f = 0.f;  // k == 15 pad row
                    s += f;
                }
                s += __shfl_xor(s, 16);
                s += __shfl_xor(s, 32);              // sum the 16 k-rows
                if (lane < 16)
                    accT[(size_t)b * MM + j0 + tn * 16 + lane] = s * (1.0f / TOPK);
            }
        }
    }
}

// ---------------------------------------------------------------------------
// K2: UPPER-TRIANGLE S-tile MFMA + adc + ls + exp.
// ls is symmetric => each unordered pair computed once (mask j>i strictly);
// tile contributes row-partials (partR[jg][i]) AND col-partials (partC[rg][j]).
// Lower-triangle tiles (jg < rg>>2) early-exit at CP cost only.
// (No max subtraction: ls in [24.7, 49.5]; verified rounds 4-11, absmax 0.)
// Grid (64, 16): 16 i-rows x 64 j-cols per tile.
// ---------------------------------------------------------------------------
__global__ __launch_bounds__(256) void k2_exp(
    const short* __restrict__ anchor, const float* __restrict__ a2,
    const float* __restrict__ accT,
    float* __restrict__ partR, float* __restrict__ partC,
    float* __restrict__ lspos)
{
    const int rg = blockIdx.x;           // 16-row group, 0..63
    const int jg = blockIdx.y;           // 64-col group, 0..15
    if (jg < (rg >> 2)) return;          // tile entirely j < i: skip

    __shared__ float pshare[4][16];
    const int tid = threadIdx.x;
    const int lane = tid & 63;
    const int wid = tid >> 6;
    const int lr = lane & 15;
    const int lg = lane >> 4;
    const int i0 = rg * 16;
    const int jcol = jg * 64 + wid * 16 + lr;

    f32x4 acc = (f32x4){0.f, 0.f, 0.f, 0.f};
    #pragma unroll
    for (int kc = 0; kc < 4; ++kc) {
        bf16x8 af = *(const bf16x8*)&anchor[(size_t)(i0 + lr) * DD + kc * 32 + lg * 8];
        bf16x8 bf = *(const bf16x8*)&anchor[(size_t)jcol * DD + kc * 32 + lg * 8];
        acc = __builtin_amdgcn_mfma_f32_16x16x32_bf16(af, bf, acc, 0, 0, 0);
    }
    const int ib4 = i0 + lg * 4;
    const float4 a2i4 = *(const float4*)&a2[ib4];
    const float a2iv[4] = {a2i4.x, a2i4.y, a2i4.z, a2i4.w};
    const float a2j = a2[jcol];
    const float4 aij4 = *(const float4*)&accT[(size_t)(jcol & (BB - 1)) * MM + ib4];
    const float aijv[4] = {aij4.x, aij4.y, aij4.z, aij4.w};

    float es[4];
    #pragma unroll
    for (int r = 0; r < 4; ++r) {
        const int i = ib4 + r;
        float g = acc[r];
        float sq = fmaxf(fmaf(-2.f, g, a2iv[r] + a2j), 0.f);
        float d0 = __builtin_amdgcn_sqrtf(sq);
        float adc = fmaf(__builtin_amdgcn_rcpf(1.f + d0), INV_T, INV_T);
        float aji = accT[(size_t)(i & (BB - 1)) * MM + jcol];
        float ls = __builtin_amdgcn_sqrtf(aijv[r] * aijv[r] + aji * aji + adc * adc);
        es[r] = (jcol > i) ? __expf(ls) : 0.f;      // strict upper triangle
        if (jcol == (i ^ BB) && jcol > i) lspos[i] = ls;  // pair (i, i+512), i<512
    }

    // column partials: sum this thread's 4 i's, then the 4 lg-groups (16 i's)
    float cs = es[0] + es[1] + es[2] + es[3];
    cs += __shfl_xor(cs, 16);
    cs += __shfl_xor(cs, 32);
    if (lg == 0) partC[(size_t)rg * MM + jcol] = cs;

    // row partials: sum 16 j's (lr lanes) per row, combine 4 waves via LDS
    #pragma unroll
    for (int r = 0; r < 4; ++r) {
        float e = es[r];
        e += __shfl_xor(e, 1);
        e += __shfl_xor(e, 2);
        e += __shfl_xor(e, 4);
        e += __shfl_xor(e, 8);
        if (lr == 0) pshare[wid][lg * 4 + r] = e;
    }
    __syncthreads();
    if (tid < 16)
        partR[(size_t)jg * MM + i0 + tid] =
            pshare[0][tid] + pshare[1][tid] + pshare[2][tid] + pshare[3][tid];
}

// ---------------------------------------------------------------------------
// K3: finish — rowsum[i] = sum of 16 row-partials + 64 col-partials;
// loss + mean, single block.
// ---------------------------------------------------------------------------
__global__ __launch_bounds__(256) void k3_finish(
    const float* __restrict__ partR, const float* __restrict__ partC,
    const float* __restrict__ lspos, float* __restrict__ out)
{
    __shared__ float red[4];
    const int tid = threadIdx.x;
    const int lane = tid & 63, w = tid >> 6;
    float lsum = 0.f;
    #pragma unroll
    for (int q = 0; q < 4; ++q) {
        const int i = tid + q * 256;
        float s = 0.f;
        #pragma unroll
        for (int jg = 0; jg < 16; ++jg) s += partR[(size_t)jg * MM + i];
        #pragma unroll
        for (int rg = 0; rg < 64; ++rg) s += partC[(size_t)rg * MM + i];
        lsum += __logf(s) - lspos[i & (BB - 1)];
    }
    #pragma unroll
    for (int off = 32; off > 0; off >>= 1) lsum += __shfl_xor(lsum, off);
    if (lane == 0) red[w] = lsum;
    __syncthreads();
    if (tid == 0) out[0] = (red[0] + red[1] + red[2] + red[3]) * (1.0f / MM);
}

// ---------------------------------------------------------------------------
extern "C" void kernel_launch(void* const* d_in, const int* in_sizes, int n_in,
                              void* d_out, int out_size, void* d_ws, size_t ws_size,
                              hipStream_t stream)
{
    const float* feat    = (const float*)d_in[0];  // (512, 2, 128) f32
    const int*   indices = (const int*)  d_in[1];  // (512,) i32
    const float* saved   = (const float*)d_in[2];  // (100000, 128) f32
    const int*   rks     = (const int*)  d_in[3];  // (100000, 50) i32

    char* w = (char*)d_ws;
    short* anchor = (short*)(w + OFF_ANCH);
    float* a2     = (float*)(w + OFF_A2);
    float* accT   = (float*)(w + OFF_ACCT);
    float* partR  = (float*)(w + OFF_PARTR);
    float* partC  = (float*)(w + OFF_PARTC);
    float* lspos  = (float*)(w + OFF_LSPOS);

    // K0: anchor -> bf16 + exact norms; zero partR/partC
    k0_anchor<<<MM / 4, 256, 0, stream>>>(feat, (unsigned*)anchor, a2,
                                          (float4*)partR);
    // K1: neighbor GEMM -> accT  (R6 exact: grid (128,4))
    k1_acc<<<dim3(128, 4), 256, 0, stream>>>(anchor, a2, indices, saved, rks, accT);
    // K2: upper-triangle S-GEMM + exp -> partR, partC, lspos
    k2_exp<<<dim3(64, 16), 256, 0, stream>>>(anchor, a2, accT, partR, partC, lspos);
    // K3: loss + mean
    k3_finish<<<1, 256, 0, stream>>>(partR, partC, lspos, (float*)d_out);
}

// Round 13
// 38.565 us; speedup vs baseline: 2.4731x; 2.4731x over previous
//
#include <hip/hip_runtime.h>
#include <math.h>

// Problem constants
#define BB 512
#define VV 2
#define MM 1024
#define DD 128
#define KMAX 50
#define TOPK 15
#define INV_T (1.0f/0.07f)

// ---------------- Workspace layout (byte offsets) ----------------
#define OFF_ANCH  0                      // bf16 [MM][DD]   256 KB
#define OFF_A2    262144                 // f32  [MM]         4 KB
#define OFF_ACCT  266240                 // f32  [BB][MM]     2 MB : accT[b][i] = acc(i,b)
#define OFF_PART  (266240 + 2097152)     // f32  [16][MM]    64 KB : per-jg partial expsums
#define OFF_LSPOS (OFF_PART + 65536)     // f32  [MM]         4 KB

typedef __attribute__((ext_vector_type(8))) short bf16x8;
typedef __attribute__((ext_vector_type(4))) float f32x4;

// f32 -> bf16 (RNE)
__device__ __forceinline__ short f2bf(float x)
{
    union { float f; unsigned u; } a; a.f = x;
    return (short)((a.u + 0x7FFFu + ((a.u >> 16) & 1u)) >> 16);
}

// convert 8 f32 (two float4) to bf16x8, accumulating sum of squares
__device__ __forceinline__ bf16x8 cvt8(float4 p0, float4 p1, float& nacc)
{
    float v[8] = {p0.x, p0.y, p0.z, p0.w, p1.x, p1.y, p1.z, p1.w};
    bf16x8 r;
    #pragma unroll
    for (int e = 0; e < 8; ++e) {
        nacc = fmaf(v[e], v[e], nacc);
        r[e] = f2bf(v[e]);
    }
    return r;
}

// ---------------------------------------------------------------------------
// K0: anchor (transposed features) -> bf16 + exact f32 norms.  (R6 verbatim)
// 256 blocks x 256 thr; wave per row.
// ---------------------------------------------------------------------------
__global__ __launch_bounds__(256) void k0_anchor(
    const float* __restrict__ feat,
    unsigned* __restrict__ anchor_u,     // bf16 pairs packed as u32
    float* __restrict__ a2)
{
    const int row  = blockIdx.x * 4 + (threadIdx.x >> 6);
    const int lane = threadIdx.x & 63;
    const int frow = (row & (BB - 1)) * VV + (row >> 9);
    float2 v = *(const float2*)&feat[(size_t)frow * DD + lane * 2];
    unsigned lo = (unsigned)(unsigned short)f2bf(v.x);
    unsigned hi = (unsigned)(unsigned short)f2bf(v.y);
    anchor_u[row * (DD / 2) + lane] = lo | (hi << 16);
    float sq = v.x * v.x + v.y * v.y;
    #pragma unroll
    for (int off = 32; off > 0; off >>= 1) sq += __shfl_xor(sq, off);
    if (lane == 0) a2[row] = sq;
}

// ---------------------------------------------------------------------------
// K1: neighbor MFMA GEMM -> accT[b][i].
// Grid (256, 4), 256 thr = 4 waves, __launch_bounds__(256,4) (VGPR <= 128).
// Block = 32 neighbor rows (2 b-groups) x 256 anchor cols; each wave owns a
// 64-col group (wid*64) over the same 32 rows. vs R6: rows/block halved ->
// 1024 blocks = 4 blocks/CU = 4 waves/SIMD (R8 showed grid-limited Occ 11%).
// A-gather replication unchanged (4x, by-blocks); extra B-re-reads are
// L2-resident bf16 (64 MB @ ~34 TB/s, cheap).
// C layout (mfma_f32_16x16x32_bf16): col = lane&15, row(k) = (lane>>4)*4 + reg.
// ---------------------------------------------------------------------------
__global__ __launch_bounds__(256, 4) void k1_acc(
    const short* __restrict__ anchor,    // bf16 [MM][DD]
    const float* __restrict__ a2,
    const int* __restrict__ indices,
    const float* __restrict__ saved, const int* __restrict__ rks,
    float* __restrict__ accT)
{
    const int tid = threadIdx.x;
    const int lane = tid & 63;
    const int wid = tid >> 6;                        // 0..3: col group
    const int lr = lane & 15;
    const int lg = lane >> 4;
    const int m0 = blockIdx.x * 32;                  // 32 neighbor rows
    const int j0 = blockIdx.y * 256 + wid * 64;      // this wave's 64 cols

    // A side: gather 2 b-groups' saved rows (k = lr; k=15 masked in epilogue)
    int aidx[2];
    #pragma unroll
    for (int tm = 0; tm < 2; ++tm) {
        int b = (m0 >> 4) + tm;                      // = bx*2 + tm
        aidx[tm] = rks[(size_t)indices[b] * KMAX + lr];
    }
    bf16x8 af[2][4];
    float nnA[2] = {0.f, 0.f};
    #pragma unroll
    for (int tm = 0; tm < 2; ++tm)
        #pragma unroll
        for (int kc = 0; kc < 4; ++kc) {
            const float4* p = (const float4*)&saved[(size_t)aidx[tm] * DD + kc * 32 + lg * 8];
            af[tm][kc] = cvt8(p[0], p[1], nnA[tm]);
        }
    #pragma unroll
    for (int tm = 0; tm < 2; ++tm) {
        nnA[tm] += __shfl_xor(nnA[tm], 16);
        nnA[tm] += __shfl_xor(nnA[tm], 32);          // lane: full norm of row lr
    }
    float nnAr[2][4];
    #pragma unroll
    for (int tm = 0; tm < 2; ++tm)
        #pragma unroll
        for (int r = 0; r < 4; ++r)
            nnAr[tm][r] = __shfl(nnA[tm], lg * 4 + r);   // norm of C-row lg*4+r

    // B side: staged bf16 anchor, MFMA accumulate
    f32x4 acc[2][4];
    #pragma unroll
    for (int a = 0; a < 2; ++a)
        #pragma unroll
        for (int b = 0; b < 4; ++b) acc[a][b] = (f32x4){0.f, 0.f, 0.f, 0.f};
    #pragma unroll
    for (int kc = 0; kc < 4; ++kc) {
        bf16x8 bf[4];
        #pragma unroll
        for (int tn = 0; tn < 4; ++tn)
            bf[tn] = *(const bf16x8*)&anchor[(size_t)(j0 + tn * 16 + lr) * DD + kc * 32 + lg * 8];
        #pragma unroll
        for (int tm = 0; tm < 2; ++tm)
            #pragma unroll
            for (int tn = 0; tn < 4; ++tn)
                acc[tm][tn] = __builtin_amdgcn_mfma_f32_16x16x32_bf16(
                    af[tm][kc], bf[tn], acc[tm][tn], 0, 0, 0);
    }

    // epilogue: f(dist), mask pad row, reduce 16 k-rows, store accT
    #pragma unroll
    for (int tm = 0; tm < 2; ++tm) {
        const int b = (m0 >> 4) + tm;
        #pragma unroll
        for (int tn = 0; tn < 4; ++tn) {
            const float a2j = a2[j0 + tn * 16 + lr];
            float s = 0.f;
            #pragma unroll
            for (int r = 0; r < 4; ++r) {
                float g = acc[tm][tn][r];
                float sq = fmaxf(fmaf(-2.f, g, a2j + nnAr[tm][r]), 0.f);
                float d = __builtin_amdgcn_sqrtf(sq);
                float f = fmaf(__builtin_amdgcn_rcpf(1.f + d), INV_T, INV_T);
                if (lg == 3 && r == 3) f = 0.f;      // k == 15 pad row
                s += f;
            }
            s += __shfl_xor(s, 16);
            s += __shfl_xor(s, 32);                  // sum the 16 k-rows
            if (lane < 16)
                accT[(size_t)b * MM + j0 + tn * 16 + lane] = s * (1.0f / TOPK);
        }
    }
}

// ---------------------------------------------------------------------------
// K2: S-tile MFMA + adc + ls + exp partial sums.  (R6 verbatim)
// Grid (64, 16): 16 i-rows x 64 j-cols per block; wave handles 16 cols.
// (No max subtraction: ls in [24.7, 49.5]; verified rounds 4-12, absmax 0.)
// ---------------------------------------------------------------------------
__global__ __launch_bounds__(256) void k2_exp(
    const short* __restrict__ anchor, const float* __restrict__ a2,
    const float* __restrict__ accT,
    float* __restrict__ part, float* __restrict__ lspos)
{
    __shared__ float pshare[4][16];
    const int tid = threadIdx.x;
    const int lane = tid & 63;
    const int wid = tid >> 6;
    const int lr = lane & 15;
    const int lg = lane >> 4;
    const int i0 = blockIdx.x * 16;
    const int jg = blockIdx.y;
    const int jcol = jg * 64 + wid * 16 + lr;

    f32x4 acc = (f32x4){0.f, 0.f, 0.f, 0.f};
    #pragma unroll
    for (int kc = 0; kc < 4; ++kc) {
        bf16x8 af = *(const bf16x8*)&anchor[(size_t)(i0 + lr) * DD + kc * 32 + lg * 8];
        bf16x8 bf = *(const bf16x8*)&anchor[(size_t)jcol * DD + kc * 32 + lg * 8];
        acc = __builtin_amdgcn_mfma_f32_16x16x32_bf16(af, bf, acc, 0, 0, 0);
    }
    const int ib4 = i0 + lg * 4;
    const float4 a2i4 = *(const float4*)&a2[ib4];
    const float a2iv[4] = {a2i4.x, a2i4.y, a2i4.z, a2i4.w};
    const float a2j = a2[jcol];
    const float4 aij4 = *(const float4*)&accT[(size_t)(jcol & (BB - 1)) * MM + ib4];
    const float aijv[4] = {aij4.x, aij4.y, aij4.z, aij4.w};

    float esum[4];
    #pragma unroll
    for (int r = 0; r < 4; ++r) {
        const int i = ib4 + r;
        float g = acc[r];
        float sq = fmaxf(fmaf(-2.f, g, a2iv[r] + a2j), 0.f);
        float d0 = __builtin_amdgcn_sqrtf(sq);
        float adc = fmaf(__builtin_amdgcn_rcpf(1.f + d0), INV_T, INV_T);
        float aji = accT[(size_t)(i & (BB - 1)) * MM + jcol];
        float ls = __builtin_amdgcn_sqrtf(aijv[r] * aijv[r] + aji * aji + adc * adc);
        esum[r] = (jcol == i) ? 0.f : __expf(ls);
        if (jcol == (i ^ BB)) lspos[i] = ls;            // the positive pair
    }
    #pragma unroll
    for (int r = 0; r < 4; ++r) {
        float e = esum[r];
        e += __shfl_xor(e, 1);
        e += __shfl_xor(e, 2);
        e += __shfl_xor(e, 4);
        e += __shfl_xor(e, 8);                          // sum 16 j's in wave
        if (lr == 0) pshare[wid][lg * 4 + r] = e;
    }
    __syncthreads();
    if (tid < 16)
        part[jg * MM + i0 + tid] =
            pshare[0][tid] + pshare[1][tid] + pshare[2][tid] + pshare[3][tid];
}

// ---------------------------------------------------------------------------
// K3: finish — loss per row + mean, single block.  (R6 verbatim)
// ---------------------------------------------------------------------------
__global__ __launch_bounds__(256) void k3_finish(
    const float* __restrict__ part, const float* __restrict__ lspos,
    float* __restrict__ out)
{
    __shared__ float red[4];
    const int tid = threadIdx.x;
    const int lane = tid & 63, w = tid >> 6;
    float lsum = 0.f;
    #pragma unroll
    for (int q = 0; q < 4; ++q) {
        const int i = tid + q * 256;
        float s = 0.f;
        #pragma unroll
        for (int jg = 0; jg < 16; ++jg) s += part[jg * MM + i];
        lsum += __logf(s) - lspos[i];
    }
    #pragma unroll
    for (int off = 32; off > 0; off >>= 1) lsum += __shfl_xor(lsum, off);
    if (lane == 0) red[w] = lsum;
    __syncthreads();
    if (tid == 0) out[0] = (red[0] + red[1] + red[2] + red[3]) * (1.0f / MM);
}

// ---------------------------------------------------------------------------
extern "C" void kernel_launch(void* const* d_in, const int* in_sizes, int n_in,
                              void* d_out, int out_size, void* d_ws, size_t ws_size,
                              hipStream_t stream)
{
    const float* feat    = (const float*)d_in[0];  // (512, 2, 128) f32
    const int*   indices = (const int*)  d_in[1];  // (512,) i32
    const float* saved   = (const float*)d_in[2];  // (100000, 128) f32
    const int*   rks     = (const int*)  d_in[3];  // (100000, 50) i32

    char* w = (char*)d_ws;
    short* anchor = (short*)(w + OFF_ANCH);
    float* a2     = (float*)(w + OFF_A2);
    float* accT   = (float*)(w + OFF_ACCT);
    float* part   = (float*)(w + OFF_PART);
    float* lspos  = (float*)(w + OFF_LSPOS);

    // K0: anchor -> bf16 + exact norms
    k0_anchor<<<MM / 4, 256, 0, stream>>>(feat, (unsigned*)anchor, a2);
    // K1: neighbor GEMM -> accT  (grid (256,4): 4 blocks/CU, A-traffic same)
    k1_acc<<<dim3(256, 4), 256, 0, stream>>>(anchor, a2, indices, saved, rks, accT);
    // K2: S-GEMM + adc + exp partials -> part, lspos
    k2_exp<<<dim3(64, 16), 256, 0, stream>>>(anchor, a2, accT, part, lspos);
    // K3: loss + mean
    k3_finish<<<1, 256, 0, stream>>>(part, lspos, (float*)d_out);
}

// Round 14
// 35.393 us; speedup vs baseline: 2.6947x; 1.0896x over previous
//
#include <hip/hip_runtime.h>
#include <math.h>

// Problem constants
#define BB 512
#define VV 2
#define MM 1024
#define DD 128
#define KMAX 50
#define TOPK 15
#define INV_T (1.0f/0.07f)

// ---------------- Workspace layout (byte offsets) ----------------
#define OFF_ANCH  0                      // bf16 [MM][DD]   256 KB
#define OFF_A2    262144                 // f32  [MM]         4 KB
#define OFF_ACCT  266240                 // f32  [BB][MM]     2 MB : accT[b][i] = acc(i,b)
#define OFF_PART  (266240 + 2097152)     // f32  [MM][16]    64 KB : TRANSPOSED partials
#define OFF_LSPOS (OFF_PART + 65536)     // f32  [MM]         4 KB

typedef __attribute__((ext_vector_type(8))) short bf16x8;
typedef __attribute__((ext_vector_type(4))) float f32x4;

// f32 -> bf16 (RNE)
__device__ __forceinline__ short f2bf(float x)
{
    union { float f; unsigned u; } a; a.f = x;
    return (short)((a.u + 0x7FFFu + ((a.u >> 16) & 1u)) >> 16);
}

// convert 8 f32 (two float4) to bf16x8, accumulating sum of squares
__device__ __forceinline__ bf16x8 cvt8(float4 p0, float4 p1, float& nacc)
{
    float v[8] = {p0.x, p0.y, p0.z, p0.w, p1.x, p1.y, p1.z, p1.w};
    bf16x8 r;
    #pragma unroll
    for (int e = 0; e < 8; ++e) {
        nacc = fmaf(v[e], v[e], nacc);
        r[e] = f2bf(v[e]);
    }
    return r;
}

// ---------------------------------------------------------------------------
// K0: anchor (transposed features) -> bf16 + exact f32 norms.  (R6 verbatim)
// 256 blocks x 256 thr; wave per row.
// ---------------------------------------------------------------------------
__global__ __launch_bounds__(256) void k0_anchor(
    const float* __restrict__ feat,
    unsigned* __restrict__ anchor_u,     // bf16 pairs packed as u32
    float* __restrict__ a2)
{
    const int row  = blockIdx.x * 4 + (threadIdx.x >> 6);
    const int lane = threadIdx.x & 63;
    const int frow = (row & (BB - 1)) * VV + (row >> 9);
    float2 v = *(const float2*)&feat[(size_t)frow * DD + lane * 2];
    unsigned lo = (unsigned)(unsigned short)f2bf(v.x);
    unsigned hi = (unsigned)(unsigned short)f2bf(v.y);
    anchor_u[row * (DD / 2) + lane] = lo | (hi << 16);
    float sq = v.x * v.x + v.y * v.y;
    #pragma unroll
    for (int off = 32; off > 0; off >>= 1) sq += __shfl_xor(sq, off);
    if (lane == 0) a2[row] = sq;
}

// ---------------------------------------------------------------------------
// K1: neighbor MFMA GEMM -> accT[b][i].  (R6 verbatim: grid (128,4), 2x2
// waves, block 64 neighbor rows x 256 anchor cols via jt loop.)
// A side gathered from saved (f32->bf16 in-register + exact shfl norms);
// B side reads K0's staged bf16 anchor.
// C layout (mfma_f32_16x16x32_bf16): col = lane&15, row(k) = (lane>>4)*4 + reg.
// ---------------------------------------------------------------------------
__global__ __launch_bounds__(256) void k1_acc(
    const short* __restrict__ anchor,    // bf16 [MM][DD]
    const float* __restrict__ a2,
    const int* __restrict__ indices,
    const float* __restrict__ saved, const int* __restrict__ rks,
    float* __restrict__ accT)
{
    const int tid = threadIdx.x;
    const int lane = tid & 63;
    const int wid = tid >> 6;
    const int lr = lane & 15;
    const int lg = lane >> 4;
    const int wr = wid >> 1;
    const int wc = wid & 1;
    const int m0 = blockIdx.x * 64 + wr * 32;        // neighbor row base

    // A side: gather 2 b-groups' saved rows (k = lr; k=15 masked in epilogue)
    int aidx[2];
    #pragma unroll
    for (int tm = 0; tm < 2; ++tm) {
        int b = (m0 >> 4) + tm;
        aidx[tm] = rks[(size_t)indices[b] * KMAX + lr];
    }
    bf16x8 af[2][4];
    float nnA[2] = {0.f, 0.f};
    #pragma unroll
    for (int tm = 0; tm < 2; ++tm)
        #pragma unroll
        for (int kc = 0; kc < 4; ++kc) {
            const float4* p = (const float4*)&saved[(size_t)aidx[tm] * DD + kc * 32 + lg * 8];
            af[tm][kc] = cvt8(p[0], p[1], nnA[tm]);
        }
    #pragma unroll
    for (int tm = 0; tm < 2; ++tm) {
        nnA[tm] += __shfl_xor(nnA[tm], 16);
        nnA[tm] += __shfl_xor(nnA[tm], 32);          // lane: full norm of row lr
    }
    float nnAr[2][4];
    #pragma unroll
    for (int tm = 0; tm < 2; ++tm)
        #pragma unroll
        for (int r = 0; r < 4; ++r)
            nnAr[tm][r] = __shfl(nnA[tm], lg * 4 + r);   // norm of C-row lg*4+r

    #pragma unroll
    for (int jt = 0; jt < 2; ++jt) {
        const int j0 = blockIdx.y * 256 + jt * 128 + wc * 64;
        f32x4 acc[2][4];
        #pragma unroll
        for (int a = 0; a < 2; ++a)
            #pragma unroll
            for (int b = 0; b < 4; ++b) acc[a][b] = (f32x4){0.f, 0.f, 0.f, 0.f};
        #pragma unroll
        for (int kc = 0; kc < 4; ++kc) {
            bf16x8 bf[4];
            #pragma unroll
            for (int tn = 0; tn < 4; ++tn)
                bf[tn] = *(const bf16x8*)&anchor[(size_t)(j0 + tn * 16 + lr) * DD + kc * 32 + lg * 8];
            #pragma unroll
            for (int tm = 0; tm < 2; ++tm)
                #pragma unroll
                for (int tn = 0; tn < 4; ++tn)
                    acc[tm][tn] = __builtin_amdgcn_mfma_f32_16x16x32_bf16(
                        af[tm][kc], bf[tn], acc[tm][tn], 0, 0, 0);
        }
        #pragma unroll
        for (int tm = 0; tm < 2; ++tm) {
            const int b = (m0 >> 4) + tm;
            #pragma unroll
            for (int tn = 0; tn < 4; ++tn) {
                const float a2j = a2[j0 + tn * 16 + lr];
                float s = 0.f;
                #pragma unroll
                for (int r = 0; r < 4; ++r) {
                    float g = acc[tm][tn][r];
                    float sq = fmaxf(fmaf(-2.f, g, a2j + nnAr[tm][r]), 0.f);
                    float d = __builtin_amdgcn_sqrtf(sq);
                    float f = fmaf(__builtin_amdgcn_rcpf(1.f + d), INV_T, INV_T);
                    if (lg == 3 && r == 3) f = 0.f;  // k == 15 pad row
                    s += f;
                }
                s += __shfl_xor(s, 16);
                s += __shfl_xor(s, 32);              // sum the 16 k-rows
                if (lane < 16)
                    accT[(size_t)b * MM + j0 + tn * 16 + lane] = s * (1.0f / TOPK);
            }
        }
    }
}

// ---------------------------------------------------------------------------
// K2: S-tile MFMA + adc + ls + exp partial sums.  (R6 except part layout)
// Grid (64, 16): 16 i-rows x 64 j-cols per block; wave handles 16 cols.
// part is TRANSPOSED: part[i*16 + jg] -> row i's 16 partials in ONE cacheline
// (fixes K3's 4KB-stride single-block pathology, cf. R12's 71us k3).
// (No max subtraction: ls in [24.7, 49.5]; verified rounds 4-13, absmax 0.)
// ---------------------------------------------------------------------------
__global__ __launch_bounds__(256) void k2_exp(
    const short* __restrict__ anchor, const float* __restrict__ a2,
    const float* __restrict__ accT,
    float* __restrict__ part, float* __restrict__ lspos)
{
    __shared__ float pshare[4][16];
    const int tid = threadIdx.x;
    const int lane = tid & 63;
    const int wid = tid >> 6;
    const int lr = lane & 15;
    const int lg = lane >> 4;
    const int i0 = blockIdx.x * 16;
    const int jg = blockIdx.y;
    const int jcol = jg * 64 + wid * 16 + lr;

    f32x4 acc = (f32x4){0.f, 0.f, 0.f, 0.f};
    #pragma unroll
    for (int kc = 0; kc < 4; ++kc) {
        bf16x8 af = *(const bf16x8*)&anchor[(size_t)(i0 + lr) * DD + kc * 32 + lg * 8];
        bf16x8 bf = *(const bf16x8*)&anchor[(size_t)jcol * DD + kc * 32 + lg * 8];
        acc = __builtin_amdgcn_mfma_f32_16x16x32_bf16(af, bf, acc, 0, 0, 0);
    }
    const int ib4 = i0 + lg * 4;
    const float4 a2i4 = *(const float4*)&a2[ib4];
    const float a2iv[4] = {a2i4.x, a2i4.y, a2i4.z, a2i4.w};
    const float a2j = a2[jcol];
    const float4 aij4 = *(const float4*)&accT[(size_t)(jcol & (BB - 1)) * MM + ib4];
    const float aijv[4] = {aij4.x, aij4.y, aij4.z, aij4.w};

    float esum[4];
    #pragma unroll
    for (int r = 0; r < 4; ++r) {
        const int i = ib4 + r;
        float g = acc[r];
        float sq = fmaxf(fmaf(-2.f, g, a2iv[r] + a2j), 0.f);
        float d0 = __builtin_amdgcn_sqrtf(sq);
        float adc = fmaf(__builtin_amdgcn_rcpf(1.f + d0), INV_T, INV_T);
        float aji = accT[(size_t)(i & (BB - 1)) * MM + jcol];
        float ls = __builtin_amdgcn_sqrtf(aijv[r] * aijv[r] + aji * aji + adc * adc);
        esum[r] = (jcol == i) ? 0.f : __expf(ls);
        if (jcol == (i ^ BB)) lspos[i] = ls;            // the positive pair
    }
    #pragma unroll
    for (int r = 0; r < 4; ++r) {
        float e = esum[r];
        e += __shfl_xor(e, 1);
        e += __shfl_xor(e, 2);
        e += __shfl_xor(e, 4);
        e += __shfl_xor(e, 8);                          // sum 16 j's in wave
        if (lr == 0) pshare[wid][lg * 4 + r] = e;
    }
    __syncthreads();
    if (tid < 16)
        part[(size_t)(i0 + tid) * 16 + jg] =             // TRANSPOSED store
            pshare[0][tid] + pshare[1][tid] + pshare[2][tid] + pshare[3][tid];
}

// ---------------------------------------------------------------------------
// K3: finish — loss per row + mean, single block.
// part now row-contiguous: thread i reads part[i*16..i*16+15] (one line),
// bit-identical jg summation order.
// ---------------------------------------------------------------------------
__global__ __launch_bounds__(256) void k3_finish(
    const float* __restrict__ part, const float* __restrict__ lspos,
    float* __restrict__ out)
{
    __shared__ float red[4];
    const int tid = threadIdx.x;
    const int lane = tid & 63, w = tid >> 6;
    float lsum = 0.f;
    #pragma unroll
    for (int q = 0; q < 4; ++q) {
        const int i = tid + q * 256;
        float s = 0.f;
        #pragma unroll
        for (int jg = 0; jg < 16; ++jg) s += part[(size_t)i * 16 + jg];
        lsum += __logf(s) - lspos[i];
    }
    #pragma unroll
    for (int off = 32; off > 0; off >>= 1) lsum += __shfl_xor(lsum, off);
    if (lane == 0) red[w] = lsum;
    __syncthreads();
    if (tid == 0) out[0] = (red[0] + red[1] + red[2] + red[3]) * (1.0f / MM);
}

// ---------------------------------------------------------------------------
extern "C" void kernel_launch(void* const* d_in, const int* in_sizes, int n_in,
                              void* d_out, int out_size, void* d_ws, size_t ws_size,
                              hipStream_t stream)
{
    const float* feat    = (const float*)d_in[0];  // (512, 2, 128) f32
    const int*   indices = (const int*)  d_in[1];  // (512,) i32
    const float* saved   = (const float*)d_in[2];  // (100000, 128) f32
    const int*   rks     = (const int*)  d_in[3];  // (100000, 50) i32

    char* w = (char*)d_ws;
    short* anchor = (short*)(w + OFF_ANCH);
    float* a2     = (float*)(w + OFF_A2);
    float* accT   = (float*)(w + OFF_ACCT);
    float* part   = (float*)(w + OFF_PART);
    float* lspos  = (float*)(w + OFF_LSPOS);

    // K0: anchor -> bf16 + exact norms
    k0_anchor<<<MM / 4, 256, 0, stream>>>(feat, (unsigned*)anchor, a2);
    // K1: neighbor GEMM -> accT  (R6 exact: grid (128,4))
    k1_acc<<<dim3(128, 4), 256, 0, stream>>>(anchor, a2, indices, saved, rks, accT);
    // K2: S-GEMM + adc + exp partials -> part (transposed), lspos
    k2_exp<<<dim3(64, 16), 256, 0, stream>>>(anchor, a2, accT, part, lspos);
    // K3: loss + mean (coalesced part reads)
    k3_finish<<<1, 256, 0, stream>>>(part, lspos, (float*)d_out);
}

// Round 15
// 34.093 us; speedup vs baseline: 2.7974x; 1.0381x over previous
//
#include <hip/hip_runtime.h>
#include <math.h>

// Problem constants
#define BB 512
#define VV 2
#define MM 1024
#define DD 128
#define KMAX 50
#define TOPK 15
#define INV_T (1.0f/0.07f)

// ---------------- Workspace layout (byte offsets) ----------------
#define OFF_ANCH  0                      // bf16 [MM][DD]   256 KB
#define OFF_A2    262144                 // f32  [MM]         4 KB
#define OFF_ACCT  266240                 // f32  [BB][MM]     2 MB : accT[b][i] = acc(i,b)
#define OFF_PART  (266240 + 2097152)     // f32  [MM][16]    64 KB : transposed partials
#define OFF_LSPOS (OFF_PART + 65536)     // f32  [MM]         4 KB

typedef __attribute__((ext_vector_type(8))) short bf16x8;
typedef __attribute__((ext_vector_type(4))) float f32x4;

#define PADS 132   // shorts per LDS row (128 + 4 pad)

// f32 -> bf16 (RNE)
__device__ __forceinline__ short f2bf(float x)
{
    union { float f; unsigned u; } a; a.f = x;
    return (short)((a.u + 0x7FFFu + ((a.u >> 16) & 1u)) >> 16);
}

// ---------------------------------------------------------------------------
// K0: anchor (transposed features) -> bf16 + exact f32 norms, PLUS
// prefetch-touch of the K1 gather set (saved rows via indices/rks) so the
// HBM first-touch latency is paid here, overlapped over 65K threads.
// 256 blocks x 256 thr; wave per row.
// ---------------------------------------------------------------------------
__global__ __launch_bounds__(256) void k0_anchor(
    const float* __restrict__ feat,
    const int* __restrict__ indices,
    const int* __restrict__ rks,
    const float* __restrict__ saved,
    unsigned* __restrict__ anchor_u,     // bf16 pairs packed as u32
    float* __restrict__ a2)
{
    const int tid = threadIdx.x;

    // ---- prefetch: touch one 64B segment of each gathered saved row ----
    {
        const int pr = blockIdx.x * 256 + tid;       // 0..65535
        const int b = pr & 511;
        int k = (pr >> 9) & 15; if (k > 14) k = 14;
        const int c = pr >> 13;                      // 0..7 (64B segment)
        const int idx = rks[(size_t)indices[b] * KMAX + k];
        float4 t4 = *(const float4*)&saved[(size_t)idx * DD + c * 16];
        asm volatile("" :: "v"(t4.x), "v"(t4.y), "v"(t4.z), "v"(t4.w));
    }

    // ---- anchor stage + exact norms (R6 verbatim) ----
    const int row  = blockIdx.x * 4 + (tid >> 6);
    const int lane = tid & 63;
    const int frow = (row & (BB - 1)) * VV + (row >> 9);
    float2 v = *(const float2*)&feat[(size_t)frow * DD + lane * 2];
    unsigned lo = (unsigned)(unsigned short)f2bf(v.x);
    unsigned hi = (unsigned)(unsigned short)f2bf(v.y);
    anchor_u[row * (DD / 2) + lane] = lo | (hi << 16);
    float sq = v.x * v.x + v.y * v.y;
    #pragma unroll
    for (int off = 32; off > 0; off >>= 1) sq += __shfl_xor(sq, off);
    if (lane == 0) a2[row] = sq;
}

// ---------------------------------------------------------------------------
// K1: neighbor MFMA GEMM -> accT[b][i].  Grid (128,4), 4 waves (2x2),
// block 64 neighbor rows x 256 anchor cols via jt loop.  A side now staged
// through LDS: 256 threads cooperatively gather the block's 64 saved rows
// (8 independent float4 loads each -> full MLP), convert to bf16, compute
// exact f32 row norms.  Fragments + norms then read from LDS (padded rows).
// C layout (mfma_f32_16x16x32_bf16): col = lane&15, row(k) = (lane>>4)*4+reg.
// ---------------------------------------------------------------------------
__global__ __launch_bounds__(256) void k1_acc(
    const short* __restrict__ anchor,    // bf16 [MM][DD]
    const float* __restrict__ a2,
    const int* __restrict__ indices,
    const float* __restrict__ saved, const int* __restrict__ rks,
    float* __restrict__ accT)
{
    __shared__ short As[64 * PADS];      // 16896 B
    __shared__ float nrm[64];

    const int tid = threadIdx.x;

    // ---- stage phase: 4 threads per row (seg = quarter row) ----
    {
        const int row = tid >> 2;                    // 0..63
        const int seg = tid & 3;                     // 0..3
        const int grow = blockIdx.x * 64 + row;      // global neighbor row
        const int b = grow >> 4;
        int k = grow & 15; if (k > 14) k = 14;       // pad row dups k=14
        const int idx = rks[(size_t)indices[b] * KMAX + k];
        const float4* src = (const float4*)&saved[(size_t)idx * DD + seg * 32];
        unsigned* dst = (unsigned*)&As[row * PADS + seg * 32];
        float pn = 0.f;
        #pragma unroll
        for (int c = 0; c < 8; ++c) {
            float4 v = src[c];
            pn = fmaf(v.x, v.x, fmaf(v.y, v.y, fmaf(v.z, v.z, fmaf(v.w, v.w, pn))));
            unsigned p0 = (unsigned)(unsigned short)f2bf(v.x)
                        | ((unsigned)(unsigned short)f2bf(v.y) << 16);
            unsigned p1 = (unsigned)(unsigned short)f2bf(v.z)
                        | ((unsigned)(unsigned short)f2bf(v.w) << 16);
            dst[c * 2 + 0] = p0;
            dst[c * 2 + 1] = p1;
        }
        pn += __shfl_xor(pn, 1);
        pn += __shfl_xor(pn, 2);                     // combine 4 segments
        if (seg == 0) nrm[row] = pn;
    }
    __syncthreads();

    // ---- compute phase ----
    const int lane = tid & 63;
    const int wid = tid >> 6;
    const int lr = lane & 15;
    const int lg = lane >> 4;
    const int wr = wid >> 1;
    const int wc = wid & 1;
    const int lrow0 = wr * 32;                       // this wave's local rows

    bf16x8 af[2][4];
    #pragma unroll
    for (int tm = 0; tm < 2; ++tm)
        #pragma unroll
        for (int kc = 0; kc < 4; ++kc)
            af[tm][kc] = *(const bf16x8*)&As[(lrow0 + tm * 16 + lr) * PADS + kc * 32 + lg * 8];
    float nnAr[2][4];
    #pragma unroll
    for (int tm = 0; tm < 2; ++tm)
        #pragma unroll
        for (int r = 0; r < 4; ++r)
            nnAr[tm][r] = nrm[lrow0 + tm * 16 + lg * 4 + r];   // C-row norm

    #pragma unroll
    for (int jt = 0; jt < 2; ++jt) {
        const int j0 = blockIdx.y * 256 + jt * 128 + wc * 64;
        f32x4 acc[2][4];
        #pragma unroll
        for (int a = 0; a < 2; ++a)
            #pragma unroll
            for (int b = 0; b < 4; ++b) acc[a][b] = (f32x4){0.f, 0.f, 0.f, 0.f};
        #pragma unroll
        for (int kc = 0; kc < 4; ++kc) {
            bf16x8 bf[4];
            #pragma unroll
            for (int tn = 0; tn < 4; ++tn)
                bf[tn] = *(const bf16x8*)&anchor[(size_t)(j0 + tn * 16 + lr) * DD + kc * 32 + lg * 8];
            #pragma unroll
            for (int tm = 0; tm < 2; ++tm)
                #pragma unroll
                for (int tn = 0; tn < 4; ++tn)
                    acc[tm][tn] = __builtin_amdgcn_mfma_f32_16x16x32_bf16(
                        af[tm][kc], bf[tn], acc[tm][tn], 0, 0, 0);
        }
        const int m0 = blockIdx.x * 64 + lrow0;
        #pragma unroll
        for (int tm = 0; tm < 2; ++tm) {
            const int b = (m0 >> 4) + tm;
            #pragma unroll
            for (int tn = 0; tn < 4; ++tn) {
                const float a2j = a2[j0 + tn * 16 + lr];
                float s = 0.f;
                #pragma unroll
                for (int r = 0; r < 4; ++r) {
                    float g = acc[tm][tn][r];
                    float sq = fmaxf(fmaf(-2.f, g, a2j + nnAr[tm][r]), 0.f);
                    float d = __builtin_amdgcn_sqrtf(sq);
                    float f = fmaf(__builtin_amdgcn_rcpf(1.f + d), INV_T, INV_T);
                    if (lg == 3 && r == 3) f = 0.f;  // k == 15 pad row
                    s += f;
                }
                s += __shfl_xor(s, 16);
                s += __shfl_xor(s, 32);              // sum the 16 k-rows
                if (lane < 16)
                    accT[(size_t)b * MM + j0 + tn * 16 + lane] = s * (1.0f / TOPK);
            }
        }
    }
}

// ---------------------------------------------------------------------------
// K2: S-tile MFMA + adc + ls + exp partial sums.  (R14 verbatim)
// Grid (64, 16): 16 i-rows x 64 j-cols per block; wave handles 16 cols.
// (No max subtraction: ls in [24.7, 49.5]; verified rounds 4-14, absmax 0.)
// ---------------------------------------------------------------------------
__global__ __launch_bounds__(256) void k2_exp(
    const short* __restrict__ anchor, const float* __restrict__ a2,
    const float* __restrict__ accT,
    float* __restrict__ part, float* __restrict__ lspos)
{
    __shared__ float pshare[4][16];
    const int tid = threadIdx.x;
    const int lane = tid & 63;
    const int wid = tid >> 6;
    const int lr = lane & 15;
    const int lg = lane >> 4;
    const int i0 = blockIdx.x * 16;
    const int jg = blockIdx.y;
    const int jcol = jg * 64 + wid * 16 + lr;

    f32x4 acc = (f32x4){0.f, 0.f, 0.f, 0.f};
    #pragma unroll
    for (int kc = 0; kc < 4; ++kc) {
        bf16x8 af = *(const bf16x8*)&anchor[(size_t)(i0 + lr) * DD + kc * 32 + lg * 8];
        bf16x8 bf = *(const bf16x8*)&anchor[(size_t)jcol * DD + kc * 32 + lg * 8];
        acc = __builtin_amdgcn_mfma_f32_16x16x32_bf16(af, bf, acc, 0, 0, 0);
    }
    const int ib4 = i0 + lg * 4;
    const float4 a2i4 = *(const float4*)&a2[ib4];
    const float a2iv[4] = {a2i4.x, a2i4.y, a2i4.z, a2i4.w};
    const float a2j = a2[jcol];
    const float4 aij4 = *(const float4*)&accT[(size_t)(jcol & (BB - 1)) * MM + ib4];
    const float aijv[4] = {aij4.x, aij4.y, aij4.z, aij4.w};

    float esum[4];
    #pragma unroll
    for (int r = 0; r < 4; ++r) {
        const int i = ib4 + r;
        float g = acc[r];
        float sq = fmaxf(fmaf(-2.f, g, a2iv[r] + a2j), 0.f);
        float d0 = __builtin_amdgcn_sqrtf(sq);
        float adc = fmaf(__builtin_amdgcn_rcpf(1.f + d0), INV_T, INV_T);
        float aji = accT[(size_t)(i & (BB - 1)) * MM + jcol];
        float ls = __builtin_amdgcn_sqrtf(aijv[r] * aijv[r] + aji * aji + adc * adc);
        esum[r] = (jcol == i) ? 0.f : __expf(ls);
        if (jcol == (i ^ BB)) lspos[i] = ls;            // the positive pair
    }
    #pragma unroll
    for (int r = 0; r < 4; ++r) {
        float e = esum[r];
        e += __shfl_xor(e, 1);
        e += __shfl_xor(e, 2);
        e += __shfl_xor(e, 4);
        e += __shfl_xor(e, 8);                          // sum 16 j's in wave
        if (lr == 0) pshare[wid][lg * 4 + r] = e;
    }
    __syncthreads();
    if (tid < 16)
        part[(size_t)(i0 + tid) * 16 + jg] =             // transposed store
            pshare[0][tid] + pshare[1][tid] + pshare[2][tid] + pshare[3][tid];
}

// ---------------------------------------------------------------------------
// K3: finish — loss per row + mean, single block.  (R14 verbatim)
// ---------------------------------------------------------------------------
__global__ __launch_bounds__(256) void k3_finish(
    const float* __restrict__ part, const float* __restrict__ lspos,
    float* __restrict__ out)
{
    __shared__ float red[4];
    const int tid = threadIdx.x;
    const int lane = tid & 63, w = tid >> 6;
    float lsum = 0.f;
    #pragma unroll
    for (int q = 0; q < 4; ++q) {
        const int i = tid + q * 256;
        float s = 0.f;
        #pragma unroll
        for (int jg = 0; jg < 16; ++jg) s += part[(size_t)i * 16 + jg];
        lsum += __logf(s) - lspos[i];
    }
    #pragma unroll
    for (int off = 32; off > 0; off >>= 1) lsum += __shfl_xor(lsum, off);
    if (lane == 0) red[w] = lsum;
    __syncthreads();
    if (tid == 0) out[0] = (red[0] + red[1] + red[2] + red[3]) * (1.0f / MM);
}

// ---------------------------------------------------------------------------
extern "C" void kernel_launch(void* const* d_in, const int* in_sizes, int n_in,
                              void* d_out, int out_size, void* d_ws, size_t ws_size,
                              hipStream_t stream)
{
    const float* feat    = (const float*)d_in[0];  // (512, 2, 128) f32
    const int*   indices = (const int*)  d_in[1];  // (512,) i32
    const float* saved   = (const float*)d_in[2];  // (100000, 128) f32
    const int*   rks     = (const int*)  d_in[3];  // (100000, 50) i32

    char* w = (char*)d_ws;
    short* anchor = (short*)(w + OFF_ANCH);
    float* a2     = (float*)(w + OFF_A2);
    float* accT   = (float*)(w + OFF_ACCT);
    float* part   = (float*)(w + OFF_PART);
    float* lspos  = (float*)(w + OFF_LSPOS);

    // K0: anchor -> bf16 + exact norms; prefetch-touch K1's gather set
    k0_anchor<<<MM / 4, 256, 0, stream>>>(feat, indices, rks, saved,
                                          (unsigned*)anchor, a2);
    // K1: neighbor GEMM -> accT (LDS-staged A gather)
    k1_acc<<<dim3(128, 4), 256, 0, stream>>>(anchor, a2, indices, saved, rks, accT);
    // K2: S-GEMM + adc + exp partials -> part (transposed), lspos
    k2_exp<<<dim3(64, 16), 256, 0, stream>>>(anchor, a2, accT, part, lspos);
    // K3: loss + mean
    k3_finish<<<1, 256, 0, stream>>>(part, lspos, (float*)d_out);
}